// Round 1
// baseline (1364.031 us; speedup 1.0000x reference)
//
#include <hip/hip_runtime.h>

#define B_ 1024
#define L_ 2048
#define C_ 12

// ---------------- helpers ----------------
__device__ __forceinline__ float RL(float v, int l) {
  return __uint_as_float(__builtin_amdgcn_readlane(__float_as_uint(v), (unsigned)l));
}
__device__ __forceinline__ float frcp(float x) { return __builtin_amdgcn_rcpf(x); }
// tanh(x) = 2*sigmoid(2x)-1 ; robust for large |x| (exp->inf gives rcp->0 -> -1)
__device__ __forceinline__ float ftanh(float x) {
  float e = __expf(-2.f * x);
  return 2.f * frcp(1.f + e) - 1.f;
}
// gate activation: sigmoid for i/f/o lanes, tanh for g lanes
__device__ __forceinline__ float actg(float g, bool isg) {
  float z = isg ? 2.f * g : g;
  float e = __expf(-z);
  float s = frcp(1.f + e);
  return isg ? 2.f * s - 1.f : s;
}

// ---------------- kernel A: local proj + 2-layer LSTM scan ----------------
// one wave per batch element; lane = gate index (0..47); stops at len.
__global__ __launch_bounds__(64) void hsmm_lstm(
    const float* __restrict__ x, const int* __restrict__ lengths,
    const float* __restrict__ lW, const float* __restrict__ lb,
    const float* __restrict__ Wih0, const float* __restrict__ Whh0,
    const float* __restrict__ bih0, const float* __restrict__ bhh0,
    const float* __restrict__ Wih1, const float* __restrict__ Whh1,
    const float* __restrict__ bih1, const float* __restrict__ bhh1,
    float* __restrict__ enc)
{
  const int b = blockIdx.x;
  const int lane = threadIdx.x;
  const int len = lengths[b];
  const float* xb = x + (size_t)b * L_ * C_;
  float* encb = enc + (size_t)b * L_ * C_;

  const int wr = (lane < 48) ? lane : 0;   // gate row
  const int cr = (lane < 12) ? lane : 0;   // channel row
  float wl[12], wa[12], wbh[12], wc1[12], wd1[12];
#pragma unroll
  for (int j = 0; j < 12; j++) {
    wl[j]  = lW[cr * 12 + j];
    wa[j]  = Wih0[wr * 12 + j];
    wbh[j] = Whh0[wr * 12 + j];
    wc1[j] = Wih1[wr * 12 + j];
    wd1[j] = Whh1[wr * 12 + j];
  }
  const float blc = lb[cr];
  const float bg0 = bih0[wr] + bhh0[wr];
  const float bg1 = bih1[wr] + bhh1[wr];
  const bool isg = (lane >= 24 && lane < 36);

  float c0 = 0.f, c1 = 0.f;        // cell state, valid on lanes<12
  float h0s[12], h1s[12];          // broadcast copies of hidden states
#pragma unroll
  for (int j = 0; j < 12; j++) { h0s[j] = 0.f; h1s[j] = 0.f; }

  // lanes 0..47 hold x for 4 timesteps: lane = s*12+c
  float xcur = xb[wr];
  for (int t0 = 0; t0 < len; t0 += 4) {
    int nidx = (t0 + 4) * C_ + wr;
    if (nidx >= L_ * C_) nidx = 0;
    float xnext = xb[nidx];          // prefetch (covered by 4 steps of compute)
#pragma unroll
    for (int s = 0; s < 4; s++) {
      if (t0 + s < len) {
        // broadcast raw x
        float xs_[12];
#pragma unroll
        for (int j = 0; j < 12; j++) xs_[j] = RL(xcur, s * 12 + j);
        // local projection (lane<12 meaningful)
        float la = blc, lb2 = 0.f;
#pragma unroll
        for (int j = 0; j < 12; j += 2) { la += wl[j] * xs_[j]; lb2 += wl[j + 1] * xs_[j + 1]; }
        float xlv = ftanh(la + lb2);
        float xls[12];
#pragma unroll
        for (int j = 0; j < 12; j++) xls[j] = RL(xlv, j);
        // layer-0 gates
        float ga = bg0, gb = 0.f;
#pragma unroll
        for (int j = 0; j < 12; j += 2) { ga += wa[j] * xls[j]; gb += wa[j + 1] * xls[j + 1]; }
#pragma unroll
        for (int j = 0; j < 12; j += 2) { ga += wbh[j] * h0s[j]; gb += wbh[j + 1] * h0s[j + 1]; }
        float a0 = actg(ga + gb, isg);
        float af = __shfl(a0, lane + 12, 64);
        float ag = __shfl(a0, lane + 24, 64);
        float ao = __shfl(a0, lane + 36, 64);
        c0 = af * c0 + a0 * ag;            // lane<12: a0 is the i-gate
        float h0v = ao * ftanh(c0);
#pragma unroll
        for (int j = 0; j < 12; j++) h0s[j] = RL(h0v, j);
        // layer-1 gates
        float g1a = bg1, g1b = 0.f;
#pragma unroll
        for (int j = 0; j < 12; j += 2) { g1a += wc1[j] * h0s[j]; g1b += wc1[j + 1] * h0s[j + 1]; }
#pragma unroll
        for (int j = 0; j < 12; j += 2) { g1a += wd1[j] * h1s[j]; g1b += wd1[j + 1] * h1s[j + 1]; }
        float a1 = actg(g1a + g1b, isg);
        float af1 = __shfl(a1, lane + 12, 64);
        float ag1 = __shfl(a1, lane + 24, 64);
        float ao1 = __shfl(a1, lane + 36, 64);
        c1 = af1 * c1 + a1 * ag1;
        float h1v = ao1 * ftanh(c1);
#pragma unroll
        for (int j = 0; j < 12; j++) h1s[j] = RL(h1v, j);
        if (lane < 12) encb[(size_t)(t0 + s) * C_ + lane] = h1v;
      }
    }
    xcur = xnext;
  }
}

// ---------------- kernel B: attention MLP + online softmax + weighted sum ----
// block = 256 (4 waves) per batch; each lane owns 2 hidden units (weights in VGPRs).
__global__ __launch_bounds__(256) void hsmm_attn(
    const float* __restrict__ enc, const int* __restrict__ lengths,
    const float* __restrict__ W1, const float* __restrict__ b1,
    const float* __restrict__ W2, const float* __restrict__ b2,
    float* __restrict__ xenc)
{
  const int b = blockIdx.x, tid = threadIdx.x;
  const int lane = tid & 63, w = tid >> 6;
  const int len = lengths[b];
  const float invlen = 1.f / (float)len;

  const int ua = 2 * lane, ub = 2 * lane + 1;
  float w1a[13], w1b[13];
#pragma unroll
  for (int k = 0; k < 13; k++) { w1a[k] = W1[ua * 13 + k]; w1b[k] = W1[ub * 13 + k]; }
  const float b1a = b1[ua], b1b = b1[ub], w2a = W2[ua], w2b = W2[ub], b2v = b2[0];

  // constant score of padded positions: feat = [1, 0 x 12]
  float pp = w2a * ftanh(b1a + w1a[0]) + w2b * ftanh(b1b + w1b[0]);
#pragma unroll
  for (int off = 1; off < 64; off <<= 1) pp += __shfl_xor(pp, off, 64);
  const float s_pad = pp + b2v;

  const float* encb = enc + (size_t)b * L_ * C_;
  float m = -1e30f, Z = 0.f, acc = 0.f;   // acc meaningful on lanes<12

  for (int base = w * 5; base < len; base += 20) {
    int lof = base + lane / 12;
    float st = 0.f;
    if (lane < 60 && lof < len) st = encb[(size_t)lof * C_ + (lane % 12)];
#pragma unroll
    for (int s = 0; s < 5; s++) {
      int l = base + s;
      if (l < len) {
        float ratio = (float)l * invlen;
        float ha = b1a + w1a[0] * ratio, hb = b1b + w1b[0] * ratio;
#pragma unroll
        for (int j = 0; j < 12; j++) {
          float ev = RL(st, s * 12 + j);
          ha += w1a[j + 1] * ev; hb += w1b[j + 1] * ev;
        }
        float p = w2a * ftanh(ha) + w2b * ftanh(hb);
#pragma unroll
        for (int off = 1; off < 64; off <<= 1) p += __shfl_xor(p, off, 64);
        float sc = p + b2v;
        float mn = fmaxf(m, sc);
        float scale = __expf(m - mn);
        float pv = __expf(sc - mn);
        Z = Z * scale + pv;
        float ev2 = __shfl(st, s * 12 + lane, 64);  // lane c gets e[c]
        acc = acc * scale + pv * ev2;
        m = mn;
      }
    }
  }

  __shared__ float sm[4], sz[4], sa[4][12];
  if (lane == 0) { sm[w] = m; sz[w] = Z; }
  if (lane < 12) sa[w][lane] = acc;
  __syncthreads();
  if (tid < 12) {
    float mm = fmaxf(fmaxf(sm[0], sm[1]), fmaxf(sm[2], sm[3]));
    if (len < L_) mm = fmaxf(mm, s_pad);
    float Zt = 0.f, at = 0.f;
#pragma unroll
    for (int v = 0; v < 4; v++) {
      float scv = __expf(sm[v] - mm);
      Zt += sz[v] * scv;
      at += sa[v][tid] * scv;
    }
    if (len < L_) Zt += (float)(L_ - len) * __expf(s_pad - mm);
    xenc[b * C_ + tid] = at / Zt;
  }
}

// ---------------- kernel C: mode cell + template machinery -> mode_emb, ird --
__device__ __forceinline__ float qcv(int q, int c) {
  // TEMPLATES as bitmasks over 12 pitch classes
  const unsigned masks[7] = {0x091u, 0x089u, 0x049u, 0x491u, 0x891u, 0x489u, 0x249u};
  return ((masks[q] >> c) & 1u) ? 1.f : -1.f;
}

__global__ __launch_bounds__(64) void hsmm_modes(
    const float* __restrict__ cWih, const float* __restrict__ cWhh,
    const float* __restrict__ cbih, const float* __restrict__ cbhh,
    const float* __restrict__ mqW,
    const float* __restrict__ iW1, const float* __restrict__ ib1,
    const float* __restrict__ iW2, const float* __restrict__ ib2,
    float* __restrict__ memb_out, float* __restrict__ ird_out)
{
  const int lane = threadIdx.x;
  const int wr = (lane < 48) ? lane : 0;
  // mode cell: o==hx always, so fold Wih+Whh
  float wc[12];
#pragma unroll
  for (int j = 0; j < 12; j++) wc[j] = cWih[wr * 12 + j] + cWhh[wr * 12 + j];
  const float bc = cbih[wr] + cbhh[wr];
  const bool isg = (lane >= 24 && lane < 36);
  float cx = 0.f;
  float hs[12];
#pragma unroll
  for (int j = 0; j < 12; j++) hs[j] = 0.f;

  __shared__ float semb[4][12];
#pragma unroll
  for (int it = 0; it < 4; it++) {
    float ga = bc, gb = 0.f;
#pragma unroll
    for (int j = 0; j < 12; j += 2) { ga += wc[j] * hs[j]; gb += wc[j + 1] * hs[j + 1]; }
    float a = actg(ga + gb, isg);
    float af = __shfl(a, lane + 12, 64);
    float ag = __shfl(a, lane + 24, 64);
    float ao = __shfl(a, lane + 36, 64);
    cx = af * cx + a * ag;
    float hv = ao * ftanh(cx);
#pragma unroll
    for (int j = 0; j < 12; j++) hs[j] = RL(hv, j);
    if (lane < 12) { semb[it][lane] = hv; memb_out[it * 12 + lane] = hv; }
  }
  __syncthreads();

  // mre[m][r][c] = sum_k emb[m][k] * mqW[(r*12+c)*12 + k]
  __shared__ float smre[4][12][12];
#pragma unroll
  for (int i = 0; i < 9; i++) {
    int o = lane + 64 * i;
    int mm = o / 144, rc = o % 144, rr = rc / 12, cc = rc % 12;
    float accv = 0.f;
#pragma unroll
    for (int k = 0; k < 12; k++) accv += semb[mm][k] * mqW[rc * 12 + k];
    smre[mm][rr][cc] = accv;
  }
  // stage init MLP weights in LDS
  __shared__ float siW1[3072];
  __shared__ float siW2[128];
  for (int i = lane; i < 3072; i += 64) siW1[i] = iW1[i];
  for (int i = lane; i < 128; i += 64) siW2[i] = iW2[i];
  __syncthreads();

  // tasks: 0..47 -> (m,r) rolled-template marginals; 48..51 -> rest feature
  int mm = (lane < 48) ? (lane / 12) : min(lane - 48, 3);
  int rr = lane % 12;
  float feat[24];
#pragma unroll
  for (int k = 0; k < 12; k++) feat[k] = semb[mm][k];
  if (lane < 48) {
    float eq[7];
#pragma unroll
    for (int q = 0; q < 7; q++) {
      float s = 0.f;
#pragma unroll
      for (int c = 0; c < 12; c++) s += smre[mm][rr][c] * qcv(q, (c - rr + 12) % 12);
      eq[q] = s;
    }
    float mx = eq[0];
#pragma unroll
    for (int q = 1; q < 7; q++) mx = fmaxf(mx, eq[q]);
    float den = 0.f;
#pragma unroll
    for (int q = 0; q < 7; q++) { eq[q] = __expf(eq[q] - mx); den += eq[q]; }
    float iden = frcp(den);
#pragma unroll
    for (int c = 0; c < 12; c++) {
      float s = 0.f;
#pragma unroll
      for (int q = 0; q < 7; q++) s += eq[q] * qcv(q, (c - rr + 12) % 12);
      feat[12 + c] = s * iden;
    }
  } else {
#pragma unroll
    for (int c = 0; c < 12; c++) feat[12 + c] = -1.f;
  }
  // init MLP 24->128->1
  float sc = ib2[0];
  for (int j = 0; j < 128; j++) {
    float h = ib1[j];
#pragma unroll
    for (int k = 0; k < 24; k++) h += siW1[j * 24 + k] * feat[k];
    sc += siW2[j] * ftanh(h);
  }
  __shared__ float sirl[52];
  if (lane < 52) sirl[lane] = sc;
  __syncthreads();

  __shared__ float sird[4][13];
  if (lane < 4) {
    float v[13];
#pragma unroll
    for (int i = 0; i < 12; i++) v[i] = sirl[lane * 12 + i];
    v[12] = sirl[48 + lane];
    float mx = v[0];
#pragma unroll
    for (int i = 1; i < 13; i++) mx = fmaxf(mx, v[i]);
    float den = 0.f;
#pragma unroll
    for (int i = 0; i < 13; i++) { v[i] = __expf(v[i] - mx); den += v[i]; }
    float iden = frcp(den);
#pragma unroll
    for (int i = 0; i < 13; i++) sird[lane][i] = v[i] * iden;
  }
  __syncthreads();
  if (lane < 48) {
    int m_ = lane / 12, i_ = lane % 12;
#pragma unroll
    for (int r = 0; r < 12; r++) ird_out[lane * 13 + r] = sird[m_][(r - i_ + 12) % 12];
    ird_out[lane * 13 + 12] = sird[m_][12];
  }
}

// ---------------- kernel D: mode_dist, shift MLP, final output --------------
__global__ __launch_bounds__(128) void hsmm_out(
    const float* __restrict__ xenc, const float* __restrict__ memb,
    const float* __restrict__ ird,
    const float* __restrict__ sW1, const float* __restrict__ sb1,
    const float* __restrict__ sW2, const float* __restrict__ sb2,
    float* __restrict__ out)
{
  const int b = blockIdx.x, tid = threadIdx.x;
  __shared__ float sxe[12], se[48], sirdl[48 * 13], hbuf[128], key[48], md[4], ssh[12];
  __shared__ float shW1[3072], shW2[1536];
  if (tid < 12) sxe[tid] = xenc[b * 12 + tid];
  if (tid < 48) se[tid] = memb[tid];
  for (int i = tid; i < 624; i += 128) sirdl[i] = ird[i];
  for (int i = tid; i < 3072; i += 128) shW1[i] = sW1[i];
  for (int i = tid; i < 1536; i += 128) shW2[i] = sW2[i];
  __syncthreads();
  if (tid == 0) {
    float lg[4]; float mx = -1e30f;
#pragma unroll
    for (int mj = 0; mj < 4; mj++) {
      float s = 0.f;
#pragma unroll
      for (int c = 0; c < 12; c++) s += sxe[c] * se[mj * 12 + c];
      lg[mj] = s; mx = fmaxf(mx, s);
    }
    float den = 0.f;
#pragma unroll
    for (int mj = 0; mj < 4; mj++) { lg[mj] = __expf(lg[mj] - mx); den += lg[mj]; }
    float iden = frcp(den);
#pragma unroll
    for (int mj = 0; mj < 4; mj++) md[mj] = lg[mj] * iden;
  }
  __syncthreads();
  for (int mj = 0; mj < 4; mj++) {
    float hv = sb1[tid];
#pragma unroll
    for (int k = 0; k < 12; k++) hv += shW1[tid * 24 + k] * se[mj * 12 + k];
#pragma unroll
    for (int k = 0; k < 12; k++) hv += shW1[tid * 24 + 12 + k] * sxe[k];
    hbuf[tid] = ftanh(hv);
    __syncthreads();
    if (tid < 12) {
      float s = sb2[tid];
      for (int j = 0; j < 128; j++) s += shW2[tid * 128 + j] * hbuf[j];
      ssh[tid] = s;
    }
    __syncthreads();
    if (tid < 12) {
      float mx = ssh[0];
#pragma unroll
      for (int c = 1; c < 12; c++) mx = fmaxf(mx, ssh[c]);
      float den = 0.f;
#pragma unroll
      for (int c = 0; c < 12; c++) den += __expf(ssh[c] - mx);
      key[mj * 12 + tid] = md[mj] * __expf(ssh[tid] - mx) * frcp(den);
    }
    __syncthreads();
  }
  if (tid < 13) {
    float s = 0.f;
#pragma unroll
    for (int k = 0; k < 48; k++) s += key[k] * sirdl[k * 13 + tid];
    out[b * 13 + tid] = s;
  }
}

// ---------------- launch ----------------
extern "C" void kernel_launch(void* const* d_in, const int* in_sizes, int n_in,
                              void* d_out, int out_size, void* d_ws, size_t ws_size,
                              hipStream_t stream)
{
  const float* x    = (const float*)d_in[0];
  const int*   lens = (const int*)  d_in[1];
  const float* lW   = (const float*)d_in[2];
  const float* lb   = (const float*)d_in[3];
  const float* Wih0 = (const float*)d_in[4];
  const float* Whh0 = (const float*)d_in[5];
  const float* bih0 = (const float*)d_in[6];
  const float* bhh0 = (const float*)d_in[7];
  const float* Wih1 = (const float*)d_in[8];
  const float* Whh1 = (const float*)d_in[9];
  const float* bih1 = (const float*)d_in[10];
  const float* bhh1 = (const float*)d_in[11];
  const float* aW1  = (const float*)d_in[12];
  const float* ab1  = (const float*)d_in[13];
  const float* aW2  = (const float*)d_in[14];
  const float* ab2  = (const float*)d_in[15];
  const float* cWih = (const float*)d_in[16];
  const float* cWhh = (const float*)d_in[17];
  const float* cbih = (const float*)d_in[18];
  const float* cbhh = (const float*)d_in[19];
  const float* sW1  = (const float*)d_in[20];
  const float* sb1  = (const float*)d_in[21];
  const float* sW2  = (const float*)d_in[22];
  const float* sb2  = (const float*)d_in[23];
  const float* iW1  = (const float*)d_in[24];
  const float* ib1  = (const float*)d_in[25];
  const float* iW2  = (const float*)d_in[26];
  const float* ib2  = (const float*)d_in[27];
  const float* mqW  = (const float*)d_in[28];

  float* ws   = (float*)d_ws;
  float* enc  = ws;                                  // B*L*12 fp32 = 96 MB
  float* xenc = enc + (size_t)B_ * L_ * C_;          // B*12
  float* memb = xenc + (size_t)B_ * C_;              // 48
  float* ird  = memb + 64;                           // 48*13
  float* out  = (float*)d_out;

  hipLaunchKernelGGL(hsmm_lstm, dim3(B_), dim3(64), 0, stream,
                     x, lens, lW, lb, Wih0, Whh0, bih0, bhh0,
                     Wih1, Whh1, bih1, bhh1, enc);
  hipLaunchKernelGGL(hsmm_attn, dim3(B_), dim3(256), 0, stream,
                     enc, lens, aW1, ab1, aW2, ab2, xenc);
  hipLaunchKernelGGL(hsmm_modes, dim3(1), dim3(64), 0, stream,
                     cWih, cWhh, cbih, cbhh, mqW, iW1, ib1, iW2, ib2, memb, ird);
  hipLaunchKernelGGL(hsmm_out, dim3(B_), dim3(128), 0, stream,
                     xenc, memb, ird, sW1, sb1, sW2, sb2, out);
}

// Round 2
// 1221.817 us; speedup vs baseline: 1.1164x; 1.1164x over previous
//
#include <hip/hip_runtime.h>

#define B_ 1024
#define L_ 2048
#define C_ 12

// ---------------- helpers ----------------
__device__ __forceinline__ float RL(float v, int l) {
  return __uint_as_float(__builtin_amdgcn_readlane(__float_as_uint(v), (unsigned)l));
}
__device__ __forceinline__ float frcp(float x) { return __builtin_amdgcn_rcpf(x); }
// tanh(x) = 2*sigmoid(2x)-1 ; robust for large |x|
__device__ __forceinline__ float ftanh(float x) {
  float e = __expf(-2.f * x);
  return 2.f * frcp(1.f + e) - 1.f;
}
__device__ __forceinline__ float actg(float g, bool isg) {
  float z = isg ? 2.f * g : g;
  float e = __expf(-z);
  float s = frcp(1.f + e);
  return isg ? 2.f * s - 1.f : s;
}

// ---------------- kernel A: local proj + 2-layer LSTM scan (pipelined) ------
// One wave per batch element. Lane groups:
//   0-15 : L0 gates (i, g) for channel j = lane&15 (j<12 active)
//   16-31: L1 gates (i, g)   [lags one slot]
//   32-47: L0 gates (f, o)
//   48-63: L1 gates (f, o)
// Slot s: L0 computes h0[s], L1 computes h1[s-1]. One shared 24-long
// SGPR-broadcast fmac loop (h0 half + h1 half) serves both layers.
// Per 64-step chunk: pre0 = Wih0 @ tanh(lW@x+lb) + b0 precomputed into LDS.
__global__ __launch_bounds__(64) void hsmm_lstm(
    const float* __restrict__ x, const int* __restrict__ lengths,
    const float* __restrict__ lW, const float* __restrict__ lb,
    const float* __restrict__ Wih0, const float* __restrict__ Whh0,
    const float* __restrict__ bih0, const float* __restrict__ bhh0,
    const float* __restrict__ Wih1, const float* __restrict__ Whh1,
    const float* __restrict__ bih1, const float* __restrict__ bhh1,
    float* __restrict__ enc)
{
  const int b = blockIdx.x;
  const int lane = threadIdx.x;
  const int len = lengths[b];
  const float* xb = x + (size_t)b * L_ * C_;
  float* encb = enc + (size_t)b * L_ * C_;

  const int j = min(lane & 15, 11);
  const bool isL1 = (lane >> 4) & 1;
  const bool isF  = lane >= 32;
  const int rA = (isF ? 12 : 0) + j;   // i- or f-row
  const int rB = rA + 24;              // g- or o-row

  // per-lane weights for the shared k-loop (k<12: h0 operand, k>=12: h1 operand)
  float wA[24], wB[24];
#pragma unroll
  for (int k = 0; k < 12; k++) {
    wA[k]    = isL1 ? Wih1[rA * 12 + k] : Whh0[rA * 12 + k];
    wA[12+k] = isL1 ? Whh1[rA * 12 + k] : 0.f;
    wB[k]    = isL1 ? Wih1[rB * 12 + k] : Whh0[rB * 12 + k];
    wB[12+k] = isL1 ? Whh1[rB * 12 + k] : 0.f;
  }
  const float bA = isL1 ? (bih1[rA] + bhh1[rA]) : 0.f;
  const float bB = isL1 ? (bih1[rB] + bhh1[rB]) : 0.f;
  const float sc2 = isF ? 1.f : 2.f;     // A2: sigmoid (f/o lanes) vs tanh (i/g lanes)
  const float kk1 = isF ? 1.f : 2.f;
  const float kk0 = isF ? 0.f : -1.f;
  const bool wrE = ((lane >> 4) == 1) && ((lane & 15) < 12);  // lanes that own h1 values

  __shared__ float s_lW[156];      // lW(144) + lb(12)
  __shared__ float s_Wih0[576];
  __shared__ float s_b0[48];
  __shared__ float s_pre[64 * 48]; // pre0[t'][48]
  __shared__ float s_ebuf[64 * 12];

  for (int i = lane; i < 144; i += 64) s_lW[i] = lW[i];
  if (lane < 12) s_lW[144 + lane] = lb[lane];
  for (int i = lane; i < 576; i += 64) s_Wih0[i] = Wih0[i];
  if (lane < 48) s_b0[lane] = bih0[lane] + bhh0[lane];
  __syncthreads();

  float h0s[12], h1s[12];
#pragma unroll
  for (int k = 0; k < 12; k++) { h0s[k] = 0.f; h1s[k] = 0.f; }
  float cc = 0.f;   // c0 on lanes 0-15, c1 on lanes 16-31 (garbage elsewhere)

  for (int t0 = 0; t0 <= len; t0 += 64) {
    const int send = min(t0 + 64, len + 1);

    // ---- chunk precompute: lane handles timestep t0+lane ----
    {
      const int tt = t0 + lane;
      float xv[12];
      if (tt < L_) {
        const float4* xp = (const float4*)(xb + (size_t)tt * C_);
        float4 a0 = xp[0], a1 = xp[1], a2 = xp[2];
        xv[0]=a0.x; xv[1]=a0.y; xv[2]=a0.z; xv[3]=a0.w;
        xv[4]=a1.x; xv[5]=a1.y; xv[6]=a1.z; xv[7]=a1.w;
        xv[8]=a2.x; xv[9]=a2.y; xv[10]=a2.z; xv[11]=a2.w;
      } else {
#pragma unroll
        for (int k = 0; k < 12; k++) xv[k] = 0.f;
      }
      float xl[12];
#pragma unroll
      for (int c = 0; c < 12; c++) {
        float acc = s_lW[144 + c];
#pragma unroll
        for (int k = 0; k < 12; k++) acc += s_lW[c * 12 + k] * xv[k];
        xl[c] = ftanh(acc);
      }
      float4* prow = (float4*)(s_pre + lane * 48);
#pragma unroll
      for (int r4 = 0; r4 < 12; r4++) {
        float p[4];
#pragma unroll
        for (int q = 0; q < 4; q++) {
          const int r = r4 * 4 + q;
          float acc = s_b0[r];
#pragma unroll
          for (int k = 0; k < 12; k++) acc += s_Wih0[r * 12 + k] * xl[k];
          p[q] = acc;
        }
        prow[r4] = make_float4(p[0], p[1], p[2], p[3]);
      }
    }
    __syncthreads();

    // ---- scan slots ----
    float pA_n = s_pre[rA], pB_n = s_pre[rB];   // prefetch idx 0
    for (int s = t0; s < send; s++) {
      const int idx = s - t0;
      const float pA = pA_n, pB = pB_n;
      const int nof = (idx < 63 ? idx + 1 : 63) * 48;
      pA_n = s_pre[nof + rA]; pB_n = s_pre[nof + rB];   // prefetch next slot

      float accA = isL1 ? bA : pA;
      float accB = isL1 ? bB : pB;
#pragma unroll
      for (int k = 0; k < 12; k++) {
        accA = fmaf(wA[k], h0s[k], accA);
        accB = fmaf(wB[k], h0s[k], accB);
      }
#pragma unroll
      for (int k = 0; k < 12; k++) {
        accA = fmaf(wA[12 + k], h1s[k], accA);
        accB = fmaf(wB[12 + k], h1s[k], accB);
      }
      const float A1 = frcp(1.f + __expf(-accA));                    // sigmoid(i or f)
      const float A2 = fmaf(kk1, frcp(1.f + __expf(-accB * sc2)), kk0); // tanh(g) / sigmoid(o)
      const float T1 = __shfl_xor(A1, 32, 64);   // partner: sigmoid(f) on lanes<32
      const float T2 = __shfl_xor(A2, 32, 64);   // partner: sigmoid(o) on lanes<32
      float ccn = fmaf(T1, cc, A1 * A2);
      float hv  = T2 * ftanh(ccn);
      if (s == 0 && isL1) { ccn = 0.f; hv = 0.f; }  // discard L1 priming slot
      cc = ccn;
      if (wrE) s_ebuf[idx * 12 + (lane & 15)] = hv; // h1[s-1] -> chunk buffer
#pragma unroll
      for (int k = 0; k < 12; k++) h0s[k] = RL(hv, k);        // h0[s]
#pragma unroll
      for (int k = 0; k < 12; k++) h1s[k] = RL(hv, 16 + k);   // h1[s-1]
    }
    __syncthreads();

    // ---- flush ebuf -> enc (coalesced) ----
    if (lane < send - t0) {
      const int g = t0 + lane - 1;
      if (g >= 0 && g < len) {
        const float4* eb = (const float4*)(s_ebuf + lane * 12);
        float4 e0 = eb[0], e1 = eb[1], e2 = eb[2];
        float4* ep = (float4*)(encb + (size_t)g * C_);
        ep[0] = e0; ep[1] = e1; ep[2] = e2;
      }
    }
    __syncthreads();
  }
}

// ---------------- kernel B: attention MLP + online softmax + weighted sum ----
__global__ __launch_bounds__(256) void hsmm_attn(
    const float* __restrict__ enc, const int* __restrict__ lengths,
    const float* __restrict__ W1, const float* __restrict__ b1,
    const float* __restrict__ W2, const float* __restrict__ b2,
    float* __restrict__ xenc)
{
  const int b = blockIdx.x, tid = threadIdx.x;
  const int lane = tid & 63, w = tid >> 6;
  const int len = lengths[b];
  const float invlen = 1.f / (float)len;

  const int ua = 2 * lane, ub = 2 * lane + 1;
  float w1a[13], w1b[13];
#pragma unroll
  for (int k = 0; k < 13; k++) { w1a[k] = W1[ua * 13 + k]; w1b[k] = W1[ub * 13 + k]; }
  const float b1a = b1[ua], b1b = b1[ub], w2a = W2[ua], w2b = W2[ub], b2v = b2[0];

  float pp = w2a * ftanh(b1a + w1a[0]) + w2b * ftanh(b1b + w1b[0]);
#pragma unroll
  for (int off = 1; off < 64; off <<= 1) pp += __shfl_xor(pp, off, 64);
  const float s_pad = pp + b2v;

  const float* encb = enc + (size_t)b * L_ * C_;
  float m = -1e30f, Z = 0.f, acc = 0.f;

  for (int base = w * 5; base < len; base += 20) {
    int lof = base + lane / 12;
    float st = 0.f;
    if (lane < 60 && lof < len) st = encb[(size_t)lof * C_ + (lane % 12)];
#pragma unroll
    for (int s = 0; s < 5; s++) {
      int l = base + s;
      if (l < len) {
        float ratio = (float)l * invlen;
        float ha = b1a + w1a[0] * ratio, hb = b1b + w1b[0] * ratio;
#pragma unroll
        for (int jj = 0; jj < 12; jj++) {
          float ev = RL(st, s * 12 + jj);
          ha += w1a[jj + 1] * ev; hb += w1b[jj + 1] * ev;
        }
        float p = w2a * ftanh(ha) + w2b * ftanh(hb);
#pragma unroll
        for (int off = 1; off < 64; off <<= 1) p += __shfl_xor(p, off, 64);
        float sc = p + b2v;
        float mn = fmaxf(m, sc);
        float scale = __expf(m - mn);
        float pv = __expf(sc - mn);
        Z = Z * scale + pv;
        float ev2 = __shfl(st, s * 12 + lane, 64);
        acc = acc * scale + pv * ev2;
        m = mn;
      }
    }
  }

  __shared__ float sm[4], sz[4], sa[4][12];
  if (lane == 0) { sm[w] = m; sz[w] = Z; }
  if (lane < 12) sa[w][lane] = acc;
  __syncthreads();
  if (tid < 12) {
    float mm = fmaxf(fmaxf(sm[0], sm[1]), fmaxf(sm[2], sm[3]));
    if (len < L_) mm = fmaxf(mm, s_pad);
    float Zt = 0.f, at = 0.f;
#pragma unroll
    for (int v = 0; v < 4; v++) {
      float scv = __expf(sm[v] - mm);
      Zt += sz[v] * scv;
      at += sa[v][tid] * scv;
    }
    if (len < L_) Zt += (float)(L_ - len) * __expf(s_pad - mm);
    xenc[b * C_ + tid] = at / Zt;
  }
}

// ---------------- kernel C: mode cell + template machinery -> mode_emb, ird --
__device__ __forceinline__ float qcv(int q, int c) {
  const unsigned masks[7] = {0x091u, 0x089u, 0x049u, 0x491u, 0x891u, 0x489u, 0x249u};
  return ((masks[q] >> c) & 1u) ? 1.f : -1.f;
}

__global__ __launch_bounds__(64) void hsmm_modes(
    const float* __restrict__ cWih, const float* __restrict__ cWhh,
    const float* __restrict__ cbih, const float* __restrict__ cbhh,
    const float* __restrict__ mqW,
    const float* __restrict__ iW1, const float* __restrict__ ib1,
    const float* __restrict__ iW2, const float* __restrict__ ib2,
    float* __restrict__ memb_out, float* __restrict__ ird_out)
{
  const int lane = threadIdx.x;
  const int wr = (lane < 48) ? lane : 0;
  float wc[12];
#pragma unroll
  for (int jj = 0; jj < 12; jj++) wc[jj] = cWih[wr * 12 + jj] + cWhh[wr * 12 + jj];
  const float bc = cbih[wr] + cbhh[wr];
  const bool isg = (lane >= 24 && lane < 36);
  float cx = 0.f;
  float hs[12];
#pragma unroll
  for (int jj = 0; jj < 12; jj++) hs[jj] = 0.f;

  __shared__ float semb[4][12];
#pragma unroll
  for (int it = 0; it < 4; it++) {
    float ga = bc, gb = 0.f;
#pragma unroll
    for (int jj = 0; jj < 12; jj += 2) { ga += wc[jj] * hs[jj]; gb += wc[jj + 1] * hs[jj + 1]; }
    float a = actg(ga + gb, isg);
    float af = __shfl(a, lane + 12, 64);
    float ag = __shfl(a, lane + 24, 64);
    float ao = __shfl(a, lane + 36, 64);
    cx = af * cx + a * ag;
    float hv = ao * ftanh(cx);
#pragma unroll
    for (int jj = 0; jj < 12; jj++) hs[jj] = RL(hv, jj);
    if (lane < 12) { semb[it][lane] = hv; memb_out[it * 12 + lane] = hv; }
  }
  __syncthreads();

  __shared__ float smre[4][12][12];
#pragma unroll
  for (int i = 0; i < 9; i++) {
    int o = lane + 64 * i;
    int mm = o / 144, rc = o % 144, rr = rc / 12, ccx = rc % 12;
    float accv = 0.f;
#pragma unroll
    for (int k = 0; k < 12; k++) accv += semb[mm][k] * mqW[rc * 12 + k];
    smre[mm][rr][ccx] = accv;
  }
  __shared__ float siW1[3072];
  __shared__ float siW2[128];
  for (int i = lane; i < 3072; i += 64) siW1[i] = iW1[i];
  for (int i = lane; i < 128; i += 64) siW2[i] = iW2[i];
  __syncthreads();

  int mm = (lane < 48) ? (lane / 12) : min(lane - 48, 3);
  int rr = lane % 12;
  float feat[24];
#pragma unroll
  for (int k = 0; k < 12; k++) feat[k] = semb[mm][k];
  if (lane < 48) {
    float eq[7];
#pragma unroll
    for (int q = 0; q < 7; q++) {
      float s = 0.f;
#pragma unroll
      for (int c = 0; c < 12; c++) s += smre[mm][rr][c] * qcv(q, (c - rr + 12) % 12);
      eq[q] = s;
    }
    float mx = eq[0];
#pragma unroll
    for (int q = 1; q < 7; q++) mx = fmaxf(mx, eq[q]);
    float den = 0.f;
#pragma unroll
    for (int q = 0; q < 7; q++) { eq[q] = __expf(eq[q] - mx); den += eq[q]; }
    float iden = frcp(den);
#pragma unroll
    for (int c = 0; c < 12; c++) {
      float s = 0.f;
#pragma unroll
      for (int q = 0; q < 7; q++) s += eq[q] * qcv(q, (c - rr + 12) % 12);
      feat[12 + c] = s * iden;
    }
  } else {
#pragma unroll
    for (int c = 0; c < 12; c++) feat[12 + c] = -1.f;
  }
  float sc = ib2[0];
  for (int jj = 0; jj < 128; jj++) {
    float h = ib1[jj];
#pragma unroll
    for (int k = 0; k < 24; k++) h += siW1[jj * 24 + k] * feat[k];
    sc += siW2[jj] * ftanh(h);
  }
  __shared__ float sirl[52];
  if (lane < 52) sirl[lane] = sc;
  __syncthreads();

  __shared__ float sird[4][13];
  if (lane < 4) {
    float v[13];
#pragma unroll
    for (int i = 0; i < 12; i++) v[i] = sirl[lane * 12 + i];
    v[12] = sirl[48 + lane];
    float mx = v[0];
#pragma unroll
    for (int i = 1; i < 13; i++) mx = fmaxf(mx, v[i]);
    float den = 0.f;
#pragma unroll
    for (int i = 0; i < 13; i++) { v[i] = __expf(v[i] - mx); den += v[i]; }
    float iden = frcp(den);
#pragma unroll
    for (int i = 0; i < 13; i++) sird[lane][i] = v[i] * iden;
  }
  __syncthreads();
  if (lane < 48) {
    int m_ = lane / 12, i_ = lane % 12;
#pragma unroll
    for (int r = 0; r < 12; r++) ird_out[lane * 13 + r] = sird[m_][(r - i_ + 12) % 12];
    ird_out[lane * 13 + 12] = sird[m_][12];
  }
}

// ---------------- kernel D: mode_dist, shift MLP, final output --------------
__global__ __launch_bounds__(128) void hsmm_out(
    const float* __restrict__ xenc, const float* __restrict__ memb,
    const float* __restrict__ ird,
    const float* __restrict__ sW1, const float* __restrict__ sb1,
    const float* __restrict__ sW2, const float* __restrict__ sb2,
    float* __restrict__ out)
{
  const int b = blockIdx.x, tid = threadIdx.x;
  __shared__ float sxe[12], se[48], sirdl[48 * 13], hbuf[128], key[48], md[4], ssh[12];
  __shared__ float shW1[3072], shW2[1536];
  if (tid < 12) sxe[tid] = xenc[b * 12 + tid];
  if (tid < 48) se[tid] = memb[tid];
  for (int i = tid; i < 624; i += 128) sirdl[i] = ird[i];
  for (int i = tid; i < 3072; i += 128) shW1[i] = sW1[i];
  for (int i = tid; i < 1536; i += 128) shW2[i] = sW2[i];
  __syncthreads();
  if (tid == 0) {
    float lg[4]; float mx = -1e30f;
#pragma unroll
    for (int mj = 0; mj < 4; mj++) {
      float s = 0.f;
#pragma unroll
      for (int c = 0; c < 12; c++) s += sxe[c] * se[mj * 12 + c];
      lg[mj] = s; mx = fmaxf(mx, s);
    }
    float den = 0.f;
#pragma unroll
    for (int mj = 0; mj < 4; mj++) { lg[mj] = __expf(lg[mj] - mx); den += lg[mj]; }
    float iden = frcp(den);
#pragma unroll
    for (int mj = 0; mj < 4; mj++) md[mj] = lg[mj] * iden;
  }
  __syncthreads();
  for (int mj = 0; mj < 4; mj++) {
    float hv = sb1[tid];
#pragma unroll
    for (int k = 0; k < 12; k++) hv += shW1[tid * 24 + k] * se[mj * 12 + k];
#pragma unroll
    for (int k = 0; k < 12; k++) hv += shW1[tid * 24 + 12 + k] * sxe[k];
    hbuf[tid] = ftanh(hv);
    __syncthreads();
    if (tid < 12) {
      float s = sb2[tid];
      for (int jj = 0; jj < 128; jj++) s += shW2[tid * 128 + jj] * hbuf[jj];
      ssh[tid] = s;
    }
    __syncthreads();
    if (tid < 12) {
      float mx = ssh[0];
#pragma unroll
      for (int c = 1; c < 12; c++) mx = fmaxf(mx, ssh[c]);
      float den = 0.f;
#pragma unroll
      for (int c = 0; c < 12; c++) den += __expf(ssh[c] - mx);
      key[mj * 12 + tid] = md[mj] * __expf(ssh[tid] - mx) * frcp(den);
    }
    __syncthreads();
  }
  if (tid < 13) {
    float s = 0.f;
#pragma unroll
    for (int k = 0; k < 48; k++) s += key[k] * sirdl[k * 13 + tid];
    out[b * 13 + tid] = s;
  }
}

// ---------------- launch ----------------
extern "C" void kernel_launch(void* const* d_in, const int* in_sizes, int n_in,
                              void* d_out, int out_size, void* d_ws, size_t ws_size,
                              hipStream_t stream)
{
  const float* x    = (const float*)d_in[0];
  const int*   lens = (const int*)  d_in[1];
  const float* lW   = (const float*)d_in[2];
  const float* lb   = (const float*)d_in[3];
  const float* Wih0 = (const float*)d_in[4];
  const float* Whh0 = (const float*)d_in[5];
  const float* bih0 = (const float*)d_in[6];
  const float* bhh0 = (const float*)d_in[7];
  const float* Wih1 = (const float*)d_in[8];
  const float* Whh1 = (const float*)d_in[9];
  const float* bih1 = (const float*)d_in[10];
  const float* bhh1 = (const float*)d_in[11];
  const float* aW1  = (const float*)d_in[12];
  const float* ab1  = (const float*)d_in[13];
  const float* aW2  = (const float*)d_in[14];
  const float* ab2  = (const float*)d_in[15];
  const float* cWih = (const float*)d_in[16];
  const float* cWhh = (const float*)d_in[17];
  const float* cbih = (const float*)d_in[18];
  const float* cbhh = (const float*)d_in[19];
  const float* sW1  = (const float*)d_in[20];
  const float* sb1  = (const float*)d_in[21];
  const float* sW2  = (const float*)d_in[22];
  const float* sb2  = (const float*)d_in[23];
  const float* iW1  = (const float*)d_in[24];
  const float* ib1  = (const float*)d_in[25];
  const float* iW2  = (const float*)d_in[26];
  const float* ib2  = (const float*)d_in[27];
  const float* mqW  = (const float*)d_in[28];

  float* ws   = (float*)d_ws;
  float* enc  = ws;                                  // B*L*12 fp32 = 96 MB
  float* xenc = enc + (size_t)B_ * L_ * C_;          // B*12
  float* memb = xenc + (size_t)B_ * C_;              // 48
  float* ird  = memb + 64;                           // 48*13
  float* out  = (float*)d_out;

  hipLaunchKernelGGL(hsmm_lstm, dim3(B_), dim3(64), 0, stream,
                     x, lens, lW, lb, Wih0, Whh0, bih0, bhh0,
                     Wih1, Whh1, bih1, bhh1, enc);
  hipLaunchKernelGGL(hsmm_attn, dim3(B_), dim3(256), 0, stream,
                     enc, lens, aW1, ab1, aW2, ab2, xenc);
  hipLaunchKernelGGL(hsmm_modes, dim3(1), dim3(64), 0, stream,
                     cWih, cWhh, cbih, cbhh, mqW, iW1, ib1, iW2, ib2, memb, ird);
  hipLaunchKernelGGL(hsmm_out, dim3(B_), dim3(128), 0, stream,
                     xenc, memb, ird, sW1, sb1, sW2, sb2, out);
}